// Round 11
// baseline (138.684 us; speedup 1.0000x reference)
//
#include <hip/hip_runtime.h>
#include <hip/hip_bf16.h>

#define S 16
#define C 8
#define SC 128
#define TT 500
#define NN 1500
#define NF4 375
#define NPOW 9            // T^(2^k), k=0..8 (t <= 499 needs bit 8)

__device__ __forceinline__ float fexp2(float x) { return exp2f(x); }
__device__ __forceinline__ float flog2(float x) { return log2f(x); }

#define L2E 1.4426950408889634f
#define LN2 0.6931471805599453f

typedef float f4v __attribute__((ext_vector_type(4)));

// dst = Asrc*Bsrc per chain (8 x 16x16); 256 threads, 8 entries each.
#define MM(dst, Asrc, Bsrc) do {                                          \
    __syncthreads();                                                      \
    {   const int c_ = tid >> 5; const int e0_ = tid & 31;                \
        for (int r_ = 0; r_ < 8; ++r_) {                                  \
            const int e_ = e0_ + (r_ << 5);                               \
            const int i_ = e_ >> 4; const int l_ = e_ & 15;               \
            float acc_ = 0.f;                                             \
            _Pragma("unroll")                                             \
            for (int s_ = 0; s_ < S; ++s_)                                \
                acc_ += Asrc[(c_ * S + i_) * S + s_] *                    \
                        Bsrc[(c_ * S + s_) * S + l_];                     \
            dst[(c_ * S + i_) * S + l_] = acc_;                          \
        } }                                                               \
} while (0)

// ---------------- Kernel 1: setup + binary powers of T ---------------------
__global__ __launch_bounds__(256) void hmm_setup(
    const float* __restrict__ usi,   // (16,8)
    const float* __restrict__ ucw,   // (500,8)
    const float* __restrict__ uem,   // (16,1500)
    const float* __restrict__ utm,   // (8,16,16)
    float* __restrict__ ws_lcw,      // (500,8)   log chain weights
    float* __restrict__ ws_emlse,    // (16)      emission LSE per state
    float* __restrict__ ws_p0,       // (8,16)    initial probs [c][s]
    float* __restrict__ ws_P)        // (9,8,16,16) T^(2^k) per chain
{
    __shared__ float bufA[C * S * S];
    __shared__ float bufB[C * S * S];
    const int tid = threadIdx.x;

    // log_softmax chain weights over C per row t
    for (int t = tid; t < TT; t += 256) {
        float x[C]; float m = -1e30f;
#pragma unroll
        for (int cc = 0; cc < C; ++cc) { x[cc] = ucw[t * C + cc]; m = fmaxf(m, x[cc]); }
        float acc = 0.f;
#pragma unroll
        for (int cc = 0; cc < C; ++cc) acc += fexp2((x[cc] - m) * L2E);
        const float lse = m + flog2(acc) * LN2;
#pragma unroll
        for (int cc = 0; cc < C; ++cc) ws_lcw[t * C + cc] = x[cc] - lse;
    }

    // emission LSE per state (max-free; uem ~ N(0,1), 1500 terms => safe)
    {
        const int row = tid >> 4;
        const int ln  = tid & 15;
        const float* rp = uem + row * NN;
        float a = 0.f;
        for (int n = ln; n < NN; n += 16) a += fexp2(rp[n] * L2E);
#pragma unroll
        for (int off = 8; off >= 1; off >>= 1) a += __shfl_xor(a, off);
        if (ln == 0) ws_emlse[row] = flog2(a) * LN2;
    }

    // softmax transition rows (over s'), PROB domain -> bufA and ws_P[0]
    if (tid < SC) {
        float x[S]; float m = -1e30f;
#pragma unroll
        for (int k = 0; k < S; ++k) { x[k] = utm[tid * S + k]; m = fmaxf(m, x[k]); }
        float acc = 0.f; float e[S];
#pragma unroll
        for (int k = 0; k < S; ++k) { e[k] = fexp2((x[k] - m) * L2E); acc += e[k]; }
        const float inv = 1.f / acc;
#pragma unroll
        for (int k = 0; k < S; ++k) {
            const float v = e[k] * inv;
            bufA[tid * S + k] = v;
            ws_P[tid * S + k] = v;
        }
    }

    // p0 = softmax over states per chain -> ws_p0[c][s]
    if (tid < C) {
        const int cc = tid;
        float x[S]; float m = -1e30f;
#pragma unroll
        for (int s0 = 0; s0 < S; ++s0) { x[s0] = usi[s0 * C + cc]; m = fmaxf(m, x[s0]); }
        float acc = 0.f; float e[S];
#pragma unroll
        for (int s0 = 0; s0 < S; ++s0) { e[s0] = fexp2((x[s0] - m) * L2E); acc += e[s0]; }
        const float inv = 1.f / acc;
#pragma unroll
        for (int s0 = 0; s0 < S; ++s0) ws_p0[cc * S + s0] = e[s0] * inv;
    }

    // P[k] = P[k-1]^2, alternating LDS buffers; copy each out to ws_P
    for (int k = 1; k < NPOW; ++k) {
        if (k & 1) { MM(bufB, bufA, bufA); }
        else       { MM(bufA, bufB, bufB); }
        __syncthreads();
        const float* src = (k & 1) ? bufB : bufA;
        float* dst = ws_P + k * (C * S * S);
        for (int e = tid; e < C * S * S; e += 256) dst[e] = src[e];
    }
}

// ---------------- Kernel 2: per-block h_t (binary powering) + stream -------
// grid (3, 500), 128 threads. Each block computes h_t = p0 * prod_k P[k]
// over the set bits of t (<=8 LDS matvecs), then streams its third of the
// out2 t-slice with plain float4 stores and folds in out1's LSE.
__global__ __launch_bounds__(128) void broadcast_kernel(
    const float* __restrict__ uem,     // (16,1500)
    const float* __restrict__ ws_lcw,  // (500,8)
    const float* __restrict__ ws_emlse,// (16)
    const float* __restrict__ ws_p0,   // (8,16)
    const float* __restrict__ ws_P,    // (9,8,16,16)
    float* __restrict__ out1,          // (500,1500)
    float* __restrict__ out2,          // (500,16,8,1500)
    float* __restrict__ out3)          // (500,16,8)
{
    const int t = blockIdx.y;
    const int tid = threadIdx.x;
    __shared__ float v0[SC];
    __shared__ float v1[SC];
    __shared__ float hc[SC];
    __shared__ float Ws[S];
    __shared__ float emS[S];

    v0[tid] = ws_p0[tid];            // [c][s], c = tid>>4, s = tid&15
    if (tid < S) emS[tid] = ws_emlse[tid];
    __syncthreads();

    // v = p0 * T^t via set bits of t
    float* vin = v0;
    float* vout = v1;
    const int c = tid >> 4;
    const int sp = tid & 15;
#pragma unroll
    for (int k = 0; k < NPOW; ++k) {
        if ((t >> k) & 1) {
            const float* Pk = ws_P + k * (C * S * S) + c * (S * S) + sp;
            float acc = 0.f;
#pragma unroll
            for (int s0 = 0; s0 < S; ++s0) acc += vin[c * S + s0] * Pk[s0 * S];
            vout[tid] = acc;
            float* tmp = vin; vin = vout; vout = tmp;
            __syncthreads();
        }
    }

    // hc[s][c] = ln v + lcw[t][c]; out3 (all 3 blocks write identical data)
    {
        const float lv = flog2(vin[tid]) * LN2;   // vin[c*16+s]
        out3[(size_t)t * SC + sp * C + c] = lv;
        hc[sp * C + c] = lv + ws_lcw[t * C + c];
    }
    __syncthreads();

    if (tid < S) {
        float m = -1e30f;
#pragma unroll
        for (int cc = 0; cc < C; ++cc) m = fmaxf(m, hc[tid * C + cc]);
        float acc = 0.f;
#pragma unroll
        for (int cc = 0; cc < C; ++cc) acc += fexp2((hc[tid * C + cc] - m) * L2E);
        Ws[tid] = m + flog2(acc) * LN2;
    }
    __syncthreads();

    const int n4 = blockIdx.x * 128 + tid;     // float4 index, 375 per row
    if (n4 >= NF4) return;

    float4 es[S];
#pragma unroll
    for (int s0 = 0; s0 < S; ++s0) {
        float4 e = ((const float4*)(uem + s0 * NN))[n4];
        const float el = emS[s0];
        e.x -= el; e.y -= el; e.z -= el; e.w -= el;
        es[s0] = e;
    }

    float* o2 = out2 + (size_t)t * SC * NN + 4 * n4;
#pragma unroll
    for (int s0 = 0; s0 < S; ++s0) {
#pragma unroll
        for (int cc = 0; cc < C; ++cc) {
            const float hv = hc[s0 * C + cc];
            float4 v;
            v.x = es[s0].x + hv; v.y = es[s0].y + hv;
            v.z = es[s0].z + hv; v.w = es[s0].w + hv;
            *(float4*)(o2 + (size_t)(s0 * C + cc) * NN) = v;
        }
    }

    float4 mv = make_float4(-1e30f, -1e30f, -1e30f, -1e30f);
    float4 xs[S];
#pragma unroll
    for (int s0 = 0; s0 < S; ++s0) {
        const float w = Ws[s0];
        xs[s0].x = es[s0].x + w; mv.x = fmaxf(mv.x, xs[s0].x);
        xs[s0].y = es[s0].y + w; mv.y = fmaxf(mv.y, xs[s0].y);
        xs[s0].z = es[s0].z + w; mv.z = fmaxf(mv.z, xs[s0].z);
        xs[s0].w = es[s0].w + w; mv.w = fmaxf(mv.w, xs[s0].w);
    }
    float4 av = make_float4(0.f, 0.f, 0.f, 0.f);
#pragma unroll
    for (int s0 = 0; s0 < S; ++s0) {
        av.x += fexp2((xs[s0].x - mv.x) * L2E);
        av.y += fexp2((xs[s0].y - mv.y) * L2E);
        av.z += fexp2((xs[s0].z - mv.z) * L2E);
        av.w += fexp2((xs[s0].w - mv.w) * L2E);
    }
    float4 r;
    r.x = mv.x + flog2(av.x) * LN2;
    r.y = mv.y + flog2(av.y) * LN2;
    r.z = mv.z + flog2(av.z) * LN2;
    r.w = mv.w + flog2(av.w) * LN2;
    *(float4*)(out1 + (size_t)t * NN + 4 * n4) = r;
}

extern "C" void kernel_launch(void* const* d_in, const int* in_sizes, int n_in,
                              void* d_out, int out_size, void* d_ws, size_t ws_size,
                              hipStream_t stream)
{
    const float* usi = (const float*)d_in[0];   // (16,8)
    const float* ucw = (const float*)d_in[1];   // (500,8)
    const float* uem = (const float*)d_in[2];   // (16,1,1500)
    const float* utm = (const float*)d_in[3];   // (8,16,16)

    float* out  = (float*)d_out;
    float* out1 = out;                                   // 750000
    float* out2 = out + 750000;                          // 96000000
    float* out3 = out + 750000 + 96000000;               // 64000

    float* ws       = (float*)d_ws;
    float* ws_lcw   = ws;             // 4000
    float* ws_emlse = ws + 4000;      // 16
    float* ws_p0    = ws + 4016;      // 128
    float* ws_P     = ws + 4144;      // 9*2048 = 18432

    hmm_setup<<<1, 256, 0, stream>>>(usi, ucw, uem, utm,
                                     ws_lcw, ws_emlse, ws_p0, ws_P);
    broadcast_kernel<<<dim3(3, TT), 128, 0, stream>>>(uem, ws_lcw, ws_emlse,
                                                      ws_p0, ws_P,
                                                      out1, out2, out3);
}